// Round 2
// baseline (852.205 us; speedup 1.0000x reference)
//
#include <hip/hip_runtime.h>

typedef unsigned short u16;
typedef short bf16x8 __attribute__((ext_vector_type(8)));
typedef float f32x4 __attribute__((ext_vector_type(4)));
typedef unsigned short u16x8 __attribute__((ext_vector_type(8)));

#define GLOBAL_AS __attribute__((address_space(1)))
#define LDS_AS __attribute__((address_space(3)))
#define DEVINL __device__ __forceinline__

#define BATCH 2
#define TSEQ 2048
#define NHEAD 16
#define QK 192
#define VD 128
#define HID 2048
#define MROWS 4096
#define SCALE_QK 0.07216878364870323f   // 192^-0.5

DEVINL float b2f(u16 u) { union { unsigned i; float f; } x; x.i = ((unsigned)u) << 16; return x.f; }
DEVINL u16 f2b(float f) {
    union { float f; unsigned u; } x; x.f = f;
    unsigned r = x.u + 0x7fffu + ((x.u >> 16) & 1u);
    return (u16)(r >> 16);
}
DEVINL void gload_lds16(const u16* g, u16* l) {
    __builtin_amdgcn_global_load_lds((const GLOBAL_AS unsigned*)g, (LDS_AS unsigned*)l, 16, 0, 0);
}

// ---------------- conversion kernels ----------------

__global__ void cvt_bf16x8(const float* __restrict__ in, u16* __restrict__ out, int n8) {
    int i = blockIdx.x * 256 + threadIdx.x;
    if (i < n8) {
        const float4* p = (const float4*)(in + (size_t)i * 8);
        float4 x = p[0], y = p[1];
        u16x8 o;
        o[0] = f2b(x.x); o[1] = f2b(x.y); o[2] = f2b(x.z); o[3] = f2b(x.w);
        o[4] = f2b(y.x); o[5] = f2b(y.y); o[6] = f2b(y.z); o[7] = f2b(y.w);
        *(u16x8*)(out + (size_t)i * 8) = o;
    }
}

// in: f32 [R][C] row-major -> out: bf16 [Cpad][R], zeros for c >= C
__global__ void transpose_cvt(const float* __restrict__ in, u16* __restrict__ out,
                              int R, int C, int Cpad) {
    __shared__ float tile[32][33];
    int c0 = blockIdx.x * 32, r0 = blockIdx.y * 32;
    int tx = threadIdx.x, ty = threadIdx.y;   // 32 x 8
#pragma unroll
    for (int j = 0; j < 4; j++) {
        int r = r0 + ty + j * 8, c = c0 + tx;
        tile[ty + j * 8][tx] = (c < C) ? in[(size_t)r * C + c] : 0.f;
    }
    __syncthreads();
#pragma unroll
    for (int j = 0; j < 4; j++) {
        int oc = c0 + ty + j * 8;
        int orr = r0 + tx;
        if (oc < Cpad) out[(size_t)oc * R + orr] = f2b(tile[tx][ty + j * 8]);
    }
}

// ---------------- GEMM: C = A[M][K] * BT[N][K]^T ----------------
template<int MODE>
__global__ __launch_bounds__(256)
void gemm_bt(const u16* __restrict__ A, const u16* __restrict__ BT, int Kdim,
             void* __restrict__ out0, void* __restrict__ out1) {
    __shared__ __align__(16) u16 As[128 * 32];
    __shared__ __align__(16) u16 Bs[128 * 32];
    const int tid = threadIdx.x, lane = tid & 63, wave = tid >> 6;
    const int m0 = blockIdx.x * 128, n0 = blockIdx.y * 128;
    const int wr = wave >> 1, wc = wave & 1;

    f32x4 acc[4][4];
#pragma unroll
    for (int i = 0; i < 4; i++)
#pragma unroll
        for (int j = 0; j < 4; j++) acc[i][j] = f32x4{0.f, 0.f, 0.f, 0.f};

    const int e0 = (wave * 2 + 0) * 512 + lane * 8;
    const int e1 = (wave * 2 + 1) * 512 + lane * 8;
    const u16* gA0 = A + (size_t)(m0 + (e0 >> 5)) * Kdim + (e0 & 31);
    const u16* gA1 = A + (size_t)(m0 + (e1 >> 5)) * Kdim + (e1 & 31);
    const u16* gB0 = BT + (size_t)(n0 + (e0 >> 5)) * Kdim + (e0 & 31);
    const u16* gB1 = BT + (size_t)(n0 + (e1 >> 5)) * Kdim + (e1 & 31);
    u16* lA0 = &As[(wave * 2 + 0) * 512];
    u16* lA1 = &As[(wave * 2 + 1) * 512];
    u16* lB0 = &Bs[(wave * 2 + 0) * 512];
    u16* lB1 = &Bs[(wave * 2 + 1) * 512];

    const int arow = lane & 15, koff = (lane >> 4) * 8;

    for (int k0 = 0; k0 < Kdim; k0 += 32) {
        gload_lds16(gA0, lA0); gload_lds16(gA1, lA1);
        gload_lds16(gB0, lB0); gload_lds16(gB1, lB1);
        gA0 += 32; gA1 += 32; gB0 += 32; gB1 += 32;
        asm volatile("s_waitcnt vmcnt(0)" ::: "memory");
        __syncthreads();
        bf16x8 af[4], bfr[4];
#pragma unroll
        for (int i = 0; i < 4; i++)
            af[i] = *(const bf16x8*)&As[(wr * 64 + i * 16 + arow) * 32 + koff];
#pragma unroll
        for (int j = 0; j < 4; j++)
            bfr[j] = *(const bf16x8*)&Bs[(wc * 64 + j * 16 + arow) * 32 + koff];
#pragma unroll
        for (int i = 0; i < 4; i++)
#pragma unroll
            for (int j = 0; j < 4; j++)
                acc[i][j] = __builtin_amdgcn_mfma_f32_16x16x32_bf16(af[i], bfr[j], acc[i][j], 0, 0, 0);
        __syncthreads();
    }

#pragma unroll
    for (int i = 0; i < 4; i++)
#pragma unroll
        for (int j = 0; j < 4; j++)
#pragma unroll
            for (int r = 0; r < 4; r++) {
                int row = m0 + wr * 64 + i * 16 + (lane >> 4) * 4 + r;
                int col = n0 + wc * 64 + j * 16 + (lane & 15);
                float v = acc[i][j][r];
                if constexpr (MODE == 0) {
                    int h = col / 192, d = col % 192;
                    int b = row >> 11, t = row & 2047;
                    ((u16*)out0)[((size_t)(b * 16 + h) * 2048 + t) * 192 + d] = f2b(v);
                } else if constexpr (MODE == 1) {
                    ((float*)out0)[(size_t)row * 640 + col] = v;
                } else if constexpr (MODE == 2) {
                    int h = col >> 8, d = col & 255;
                    int b = row >> 11, t = row & 2047;
                    size_t base = (size_t)(b * 16 + h) * 2048 + t;
                    if (d < 128) ((u16*)out0)[base * 192 + d] = f2b(v);
                    else         ((u16*)out1)[base * 128 + (d - 128)] = f2b(v);
                } else {
                    ((float*)out0)[(size_t)row * 2048 + col] = v;
                }
            }
}

// ---------------- LayerNorm(512) + k_rope broadcast ----------------
__global__ __launch_bounds__(256)
void ln_krope(const float* __restrict__ kvf, const float* __restrict__ gamma,
              const float* __restrict__ beta, const float* __restrict__ freqs,
              u16* __restrict__ kvlat, u16* __restrict__ kbuf) {
    int row = blockIdx.x, tid = threadIdx.x;
    const float* x = kvf + (size_t)row * 640;
    float v0 = x[tid], v1 = x[tid + 256];
    float s = v0 + v1, sq = v0 * v0 + v1 * v1;
#pragma unroll
    for (int off = 1; off < 64; off <<= 1) { s += __shfl_xor(s, off); sq += __shfl_xor(sq, off); }
    __shared__ float ssum[4], ssq[4];
    if ((tid & 63) == 0) { ssum[tid >> 6] = s; ssq[tid >> 6] = sq; }
    __syncthreads();
    s = ssum[0] + ssum[1] + ssum[2] + ssum[3];
    sq = ssq[0] + ssq[1] + ssq[2] + ssq[3];
    float mu = s * (1.f / 512.f);
    float var = sq * (1.f / 512.f) - mu * mu;
    float rs = rsqrtf(var + 1e-5f);
    kvlat[(size_t)row * 512 + tid] = f2b((v0 - mu) * rs * gamma[tid] + beta[tid]);
    kvlat[(size_t)row * 512 + tid + 256] = f2b((v1 - mu) * rs * gamma[tid + 256] + beta[tid + 256]);
    if (tid < 32) {
        int t = row & 2047, b = row >> 11;
        float x1 = x[512 + 2 * tid], x2 = x[512 + 2 * tid + 1];
        float f = freqs[t * 32 + tid], sf, cf;
        sincosf(f, &sf, &cf);
        u16 u1 = f2b(x1 * cf - x2 * sf), u2 = f2b(x1 * sf + x2 * cf);
        for (int h = 0; h < 16; ++h) {
            size_t base = ((size_t)(b * 16 + h) * 2048 + t) * 192 + 128 + 2 * tid;
            kbuf[base] = u1; kbuf[base + 1] = u2;
        }
    }
}

// ---------------- q RoPE in-place ----------------
__global__ void q_rope(u16* __restrict__ qbuf, const float* __restrict__ freqs) {
    int gid = blockIdx.x * 256 + threadIdx.x;
    int i = gid & 31, t = (gid >> 5) & 2047, bh = gid >> 16;
    size_t base = ((size_t)bh * 2048 + t) * 192 + 128 + 2 * i;
    float x1 = b2f(qbuf[base]), x2 = b2f(qbuf[base + 1]);
    float f = freqs[t * 32 + i], sf, cf;
    sincosf(f, &sf, &cf);
    qbuf[base] = f2b(x1 * cf - x2 * sf);
    qbuf[base + 1] = f2b(x1 * sf + x2 * cf);
}

// ---------------- suffix scan: u[b,t,h*128+d] = (1/16) * sum_{s>t} v[b,s,h,d] ----------------
__global__ void suffix_scan(const u16* __restrict__ vbuf, u16* __restrict__ ubuf) {
    int bh = blockIdx.x, b = bh >> 4, h = bh & 15, d = threadIdx.x;   // 128 threads
    const u16* vp = vbuf + (size_t)bh * 2048 * 128 + d;
    float run = 0.f;
    for (int t = 2047; t >= 0; t--) {
        ubuf[((size_t)b * 2048 + t) * 2048 + h * 128 + d] = f2b(run * 0.0625f);
        run += b2f(vp[(size_t)t * 128]);
    }
}

// ---------------- Z kernel: Z[b,t,s] = sum_h exp(SCALE * q.k) (bf16) ----------------
__global__ __launch_bounds__(256)
void z_kernel(const u16* __restrict__ qbuf, const u16* __restrict__ kbuf,
              u16* __restrict__ zbuf) {
    __shared__ __align__(16) u16 Ks[64 * 192];
    const int tid = threadIdx.x, lane = tid & 63, wave = tid >> 6;
    const int s0 = blockIdx.x * 64, t0 = blockIdx.y * 64, b = blockIdx.z;
    if (s0 > t0 + 63) return;   // fully masked tile: Z never read there
    const int col = lane & 15, koff8 = (lane >> 4) * 8, rowb = (lane >> 4) * 4;

    f32x4 zacc[4];
#pragma unroll
    for (int n = 0; n < 4; n++) zacc[n] = f32x4{0.f, 0.f, 0.f, 0.f};

    for (int h = 0; h < 16; h++) {
        const size_t hrow = (size_t)(b * 16 + h) * 2048;
        bf16x8 qf[6];
        const u16* qp = qbuf + (hrow + t0 + wave * 16 + col) * 192 + koff8;
#pragma unroll
        for (int kk = 0; kk < 6; kk++) qf[kk] = *(const bf16x8*)(qp + kk * 32);
        // stage K tile, XOR-swizzled (chunk c holds global chunk c^(row&7))
#pragma unroll
        for (int j = 0; j < 6; j++) {
            int slot = (wave * 6 + j) * 64 + lane;
            int r = slot / 24, c = slot % 24, cs = c ^ (r & 7);
            gload_lds16(kbuf + (hrow + s0 + r) * 192 + cs * 8, &Ks[(wave * 6 + j) * 512]);
        }
        asm volatile("s_waitcnt vmcnt(0)" ::: "memory");
        __syncthreads();
        f32x4 e[4];
#pragma unroll
        for (int n = 0; n < 4; n++) e[n] = f32x4{0.f, 0.f, 0.f, 0.f};
#pragma unroll
        for (int kk = 0; kk < 6; kk++) {
            int ca = kk * 4 + (koff8 >> 3);
#pragma unroll
            for (int n = 0; n < 4; n++) {
                int br = n * 16 + col;
                bf16x8 kf = *(const bf16x8*)&Ks[br * 192 + ((ca ^ (br & 7)) * 8)];
                e[n] = __builtin_amdgcn_mfma_f32_16x16x32_bf16(qf[kk], kf, e[n], 0, 0, 0);
            }
        }
#pragma unroll
        for (int n = 0; n < 4; n++)
#pragma unroll
            for (int r = 0; r < 4; r++)
                zacc[n][r] += __expf(e[n][r] * SCALE_QK);
        __syncthreads();
    }
#pragma unroll
    for (int n = 0; n < 4; n++)
#pragma unroll
        for (int r = 0; r < 4; r++) {
            int tg = t0 + wave * 16 + rowb + r, sg = s0 + n * 16 + col;
            zbuf[((size_t)b * 2048 + tg) * 2048 + sg] = f2b(zacc[n][r]);
        }
}

// ---------------- PV kernel: attn = sum_{s<=t} (exp/Z) v + u ----------------
__global__ __launch_bounds__(256)
void attn_pv(const u16* __restrict__ qbuf, const u16* __restrict__ kbuf,
             const u16* __restrict__ vbuf, const u16* __restrict__ zbuf,
             const u16* __restrict__ ubuf, u16* __restrict__ attnb) {
    __shared__ __align__(16) u16 Ks[64 * 192];
    __shared__ __align__(16) u16 Vt[128 * 72];
    __shared__ __align__(16) u16 Ps[4][16 * 72];
    const int tid = threadIdx.x, lane = tid & 63, wave = tid >> 6;
    const int t0 = blockIdx.x * 64;
    const int bh = blockIdx.y, b = bh >> 4, h = bh & 15;
    const int col = lane & 15, koff8 = (lane >> 4) * 8, rowb = (lane >> 4) * 4;
    const size_t kvrow = (size_t)bh * 2048;

    bf16x8 qf[6];
    {
        const u16* qp = qbuf + (kvrow + t0 + wave * 16 + col) * 192 + koff8;
#pragma unroll
        for (int kk = 0; kk < 6; kk++) qf[kk] = *(const bf16x8*)(qp + kk * 32);
    }
    f32x4 o[8];
#pragma unroll
    for (int nt = 0; nt < 8; nt++) o[nt] = f32x4{0.f, 0.f, 0.f, 0.f};

    const int nst = t0 / 64 + 1;
    for (int st = 0; st < nst; st++) {
        const int s0 = st * 64;
#pragma unroll
        for (int j = 0; j < 6; j++) {
            int slot = (wave * 6 + j) * 64 + lane;
            int r = slot / 24, c = slot % 24, cs = c ^ (r & 7);
            gload_lds16(kbuf + (kvrow + s0 + r) * 192 + cs * 8, &Ks[(wave * 6 + j) * 512]);
        }
        {   // V^T scalar transpose stage
            int key = tid >> 2, c0v = (tid & 3) * 32;
            const u16* vp = vbuf + (kvrow + s0 + key) * 128 + c0v;
#pragma unroll
            for (int jj = 0; jj < 4; jj++) {
                bf16x8 vv = *(const bf16x8*)(vp + jj * 8);
#pragma unroll
                for (int e2 = 0; e2 < 8; e2++)
                    Vt[(c0v + jj * 8 + e2) * 72 + key] = (u16)vv[e2];
            }
        }
        asm volatile("s_waitcnt vmcnt(0)" ::: "memory");
        __syncthreads();
        // QK^T
        f32x4 s[4];
#pragma unroll
        for (int n = 0; n < 4; n++) s[n] = f32x4{0.f, 0.f, 0.f, 0.f};
#pragma unroll
        for (int kk = 0; kk < 6; kk++) {
            int ca = kk * 4 + (koff8 >> 3);
#pragma unroll
            for (int n = 0; n < 4; n++) {
                int br = n * 16 + col;
                bf16x8 kf = *(const bf16x8*)&Ks[br * 192 + ((ca ^ (br & 7)) * 8)];
                s[n] = __builtin_amdgcn_mfma_f32_16x16x32_bf16(qf[kk], kf, s[n], 0, 0, 0);
            }
        }
        // w = exp(x)/Z, causal-masked, -> Ps
#pragma unroll
        for (int n = 0; n < 4; n++)
#pragma unroll
            for (int r = 0; r < 4; r++) {
                int tg = t0 + wave * 16 + rowb + r, sg = s0 + n * 16 + col;
                float w = 0.f;
                if (sg <= tg) {
                    float z = b2f(zbuf[((size_t)b * 2048 + tg) * 2048 + sg]);
                    w = __fdividef(__expf(s[n][r] * SCALE_QK), z);
                }
                Ps[wave][(rowb + r) * 72 + n * 16 + col] = f2b(w);
            }
        // PV (Ps same-wave, Vt synced above)
#pragma unroll
        for (int kk = 0; kk < 2; kk++) {
            bf16x8 pa = *(const bf16x8*)&Ps[wave][col * 72 + kk * 32 + koff8];
#pragma unroll
            for (int nt = 0; nt < 8; nt++) {
                bf16x8 vb = *(const bf16x8*)&Vt[(nt * 16 + col) * 72 + kk * 32 + koff8];
                o[nt] = __builtin_amdgcn_mfma_f32_16x16x32_bf16(pa, vb, o[nt], 0, 0, 0);
            }
        }
        __syncthreads();
    }
#pragma unroll
    for (int nt = 0; nt < 8; nt++)
#pragma unroll
        for (int r = 0; r < 4; r++) {
            int t = t0 + wave * 16 + rowb + r, d = nt * 16 + col;
            size_t oi = ((size_t)b * 2048 + t) * 2048 + h * 128 + d;
            attnb[oi] = f2b(o[nt][r] + b2f(ubuf[oi]));
        }
}

// ---------------- launch ----------------
extern "C" void kernel_launch(void* const* d_in, const int* in_sizes, int n_in,
                              void* d_out, int out_size, void* d_ws, size_t ws_size,
                              hipStream_t stream) {
    (void)in_sizes; (void)n_in; (void)out_size;
    const float* hidden = (const float*)d_in[0];
    const float* freqs  = (const float*)d_in[1];
    const float* Wq     = (const float*)d_in[3];
    const float* Wkva   = (const float*)d_in[4];
    const float* gamma  = (const float*)d_in[5];
    const float* beta   = (const float*)d_in[6];
    const float* Wkvb   = (const float*)d_in[7];
    const float* Wout   = (const float*)d_in[8];
    float* outp = (float*)d_out;

    char* ws = (char*)d_ws;
    size_t off = 0;
    auto alloc = [&](size_t bytes) -> void* {
        void* p = ws + off; off += (bytes + 255) & ~(size_t)255; return p;
    };
    u16*   hid_b = (u16*)alloc((size_t)MROWS * HID * 2);
    u16*   WqT   = (u16*)alloc((size_t)3072 * 2048 * 2);
    u16*   WkvaT = (u16*)alloc((size_t)640 * 2048 * 2);
    u16*   WkvbT = (u16*)alloc((size_t)4096 * 512 * 2);
    u16*   WoutT = (u16*)alloc((size_t)2048 * 2048 * 2);
    u16*   qbuf  = (u16*)alloc((size_t)BATCH * NHEAD * TSEQ * QK * 2);
    float* kvf   = (float*)alloc((size_t)MROWS * 640 * 4);
    u16*   kvlat = (u16*)alloc((size_t)MROWS * 512 * 2);
    u16*   kbuf  = (u16*)alloc((size_t)BATCH * NHEAD * TSEQ * QK * 2);
    u16*   vbuf  = (u16*)alloc((size_t)BATCH * NHEAD * TSEQ * VD * 2);
    u16*   attnb = (u16*)alloc((size_t)MROWS * 2048 * 2);
    if (off > ws_size) return;
    // overlays (regions free by the time they are written):
    u16* ubuf = hid_b;   // 16.78 MB, written after gemm<0> consumed hid_b
    u16* zbuf = WqT;     // 16.78 MB, spans WqT..WkvbT (19.4 MB), all free after gemm<0>/<2>

    cvt_bf16x8<<<4096, 256, 0, stream>>>(hidden, hid_b, MROWS * HID / 8);
    dim3 tb(32, 8);
    transpose_cvt<<<dim3(96, 64), tb, 0, stream>>>(Wq, WqT, 2048, 3072, 3072);
    transpose_cvt<<<dim3(20, 64), tb, 0, stream>>>(Wkva, WkvaT, 2048, 576, 640);
    transpose_cvt<<<dim3(128, 16), tb, 0, stream>>>(Wkvb, WkvbT, 512, 4096, 4096);
    transpose_cvt<<<dim3(64, 64), tb, 0, stream>>>(Wout, WoutT, 2048, 2048, 2048);

    gemm_bt<1><<<dim3(32, 5), 256, 0, stream>>>(hid_b, WkvaT, 2048, kvf, nullptr);
    ln_krope<<<MROWS, 256, 0, stream>>>(kvf, gamma, beta, freqs, kvlat, kbuf);
    gemm_bt<2><<<dim3(32, 32), 256, 0, stream>>>(kvlat, WkvbT, 512, kbuf, vbuf);
    gemm_bt<0><<<dim3(32, 24), 256, 0, stream>>>(hid_b, WqT, 2048, qbuf, nullptr);
    q_rope<<<8192, 256, 0, stream>>>(qbuf, freqs);

    suffix_scan<<<32, 128, 0, stream>>>(vbuf, ubuf);
    z_kernel<<<dim3(32, 32, 2), 256, 0, stream>>>(qbuf, kbuf, zbuf);
    attn_pv<<<dim3(32, 32), 256, 0, stream>>>(qbuf, kbuf, vbuf, zbuf, ubuf, attnb);

    gemm_bt<3><<<dim3(32, 16), 256, 0, stream>>>(attnb, WoutT, 2048, outp, nullptr);
}

// Round 3
// 562.404 us; speedup vs baseline: 1.5153x; 1.5153x over previous
//
#include <hip/hip_runtime.h>

typedef unsigned short u16;
typedef short bf16x8 __attribute__((ext_vector_type(8)));
typedef float f32x4 __attribute__((ext_vector_type(4)));
typedef unsigned short u16x8 __attribute__((ext_vector_type(8)));

#define GLOBAL_AS __attribute__((address_space(1)))
#define LDS_AS __attribute__((address_space(3)))
#define DEVINL __device__ __forceinline__

#define BATCH 2
#define TSEQ 2048
#define NHEAD 16
#define QK 192
#define VD 128
#define HID 2048
#define MROWS 4096
#define SCALE_QK 0.07216878364870323f   // 192^-0.5

DEVINL float b2f(u16 u) { union { unsigned i; float f; } x; x.i = ((unsigned)u) << 16; return x.f; }
DEVINL u16 f2b(float f) {
    union { float f; unsigned u; } x; x.f = f;
    unsigned r = x.u + 0x7fffu + ((x.u >> 16) & 1u);
    return (u16)(r >> 16);
}
DEVINL void gload_lds16(const u16* g, u16* l) {
    __builtin_amdgcn_global_load_lds((const GLOBAL_AS unsigned*)g, (LDS_AS unsigned*)l, 16, 0, 0);
}

// ---------------- conversion kernels ----------------

__global__ void cvt_bf16x8(const float* __restrict__ in, u16* __restrict__ out, int n8) {
    int i = blockIdx.x * 256 + threadIdx.x;
    if (i < n8) {
        const float4* p = (const float4*)(in + (size_t)i * 8);
        float4 x = p[0], y = p[1];
        u16x8 o;
        o[0] = f2b(x.x); o[1] = f2b(x.y); o[2] = f2b(x.z); o[3] = f2b(x.w);
        o[4] = f2b(y.x); o[5] = f2b(y.y); o[6] = f2b(y.z); o[7] = f2b(y.w);
        *(u16x8*)(out + (size_t)i * 8) = o;
    }
}

__global__ void rope_tab_k(const float* __restrict__ freqs, float2* __restrict__ tab) {
    int i = blockIdx.x * 256 + threadIdx.x;   // 65536 = 2048*32
    float f = freqs[i], s, c;
    sincosf(f, &s, &c);
    tab[i] = make_float2(c, s);
}

// in: f32 [R][C] row-major -> out: bf16 [Cpad][R], zeros for c >= C
__global__ void transpose_cvt(const float* __restrict__ in, u16* __restrict__ out,
                              int R, int C, int Cpad) {
    __shared__ float tile[32][33];
    int c0 = blockIdx.x * 32, r0 = blockIdx.y * 32;
    int tx = threadIdx.x, ty = threadIdx.y;   // 32 x 8
#pragma unroll
    for (int j = 0; j < 4; j++) {
        int r = r0 + ty + j * 8, c = c0 + tx;
        tile[ty + j * 8][tx] = (c < C) ? in[(size_t)r * C + c] : 0.f;
    }
    __syncthreads();
#pragma unroll
    for (int j = 0; j < 4; j++) {
        int oc = c0 + ty + j * 8;
        int orr = r0 + tx;
        if (oc < Cpad) out[(size_t)oc * R + orr] = f2b(tile[tx][ty + j * 8]);
    }
}

// ---------------- GEMM: C = A[M][K] * BT[N][K]^T ----------------
template<int MODE>
__global__ __launch_bounds__(256)
void gemm_bt(const u16* __restrict__ A, const u16* __restrict__ BT, int Kdim,
             void* __restrict__ out0, void* __restrict__ out1) {
    __shared__ __align__(16) u16 As[128 * 32];
    __shared__ __align__(16) u16 Bs[128 * 32];
    const int tid = threadIdx.x, lane = tid & 63, wave = tid >> 6;
    const int m0 = blockIdx.x * 128, n0 = blockIdx.y * 128;
    const int wr = wave >> 1, wc = wave & 1;

    f32x4 acc[4][4];
#pragma unroll
    for (int i = 0; i < 4; i++)
#pragma unroll
        for (int j = 0; j < 4; j++) acc[i][j] = f32x4{0.f, 0.f, 0.f, 0.f};

    const int e0 = (wave * 2 + 0) * 512 + lane * 8;
    const int e1 = (wave * 2 + 1) * 512 + lane * 8;
    const u16* gA0 = A + (size_t)(m0 + (e0 >> 5)) * Kdim + (e0 & 31);
    const u16* gA1 = A + (size_t)(m0 + (e1 >> 5)) * Kdim + (e1 & 31);
    const u16* gB0 = BT + (size_t)(n0 + (e0 >> 5)) * Kdim + (e0 & 31);
    const u16* gB1 = BT + (size_t)(n0 + (e1 >> 5)) * Kdim + (e1 & 31);
    u16* lA0 = &As[(wave * 2 + 0) * 512];
    u16* lA1 = &As[(wave * 2 + 1) * 512];
    u16* lB0 = &Bs[(wave * 2 + 0) * 512];
    u16* lB1 = &Bs[(wave * 2 + 1) * 512];

    const int arow = lane & 15, koff = (lane >> 4) * 8;

    for (int k0 = 0; k0 < Kdim; k0 += 32) {
        gload_lds16(gA0, lA0); gload_lds16(gA1, lA1);
        gload_lds16(gB0, lB0); gload_lds16(gB1, lB1);
        gA0 += 32; gA1 += 32; gB0 += 32; gB1 += 32;
        asm volatile("s_waitcnt vmcnt(0)" ::: "memory");
        __syncthreads();
        bf16x8 af[4], bfr[4];
#pragma unroll
        for (int i = 0; i < 4; i++)
            af[i] = *(const bf16x8*)&As[(wr * 64 + i * 16 + arow) * 32 + koff];
#pragma unroll
        for (int j = 0; j < 4; j++)
            bfr[j] = *(const bf16x8*)&Bs[(wc * 64 + j * 16 + arow) * 32 + koff];
#pragma unroll
        for (int i = 0; i < 4; i++)
#pragma unroll
            for (int j = 0; j < 4; j++)
                acc[i][j] = __builtin_amdgcn_mfma_f32_16x16x32_bf16(af[i], bfr[j], acc[i][j], 0, 0, 0);
        __syncthreads();
    }

#pragma unroll
    for (int i = 0; i < 4; i++)
#pragma unroll
        for (int j = 0; j < 4; j++)
#pragma unroll
            for (int r = 0; r < 4; r++) {
                int row = m0 + wr * 64 + i * 16 + (lane >> 4) * 4 + r;
                int col = n0 + wc * 64 + j * 16 + (lane & 15);
                float v = acc[i][j][r];
                if constexpr (MODE == 0) {
                    int h = col / 192, d = col % 192;
                    int b = row >> 11, t = row & 2047;
                    ((u16*)out0)[((size_t)(b * 16 + h) * 2048 + t) * 192 + d] = f2b(v);
                } else if constexpr (MODE == 1) {
                    ((float*)out0)[(size_t)row * 640 + col] = v;
                } else if constexpr (MODE == 2) {
                    int h = col >> 8, d = col & 255;
                    int b = row >> 11, t = row & 2047;
                    size_t base = (size_t)(b * 16 + h) * 2048 + t;
                    if (d < 128) ((u16*)out0)[base * 192 + d] = f2b(v);
                    else         ((u16*)out1)[base * 128 + (d - 128)] = f2b(v);
                } else {
                    ((float*)out0)[(size_t)row * 2048 + col] = v;
                }
            }
}

// ---------------- LayerNorm(512) + k_rope broadcast ----------------
__global__ __launch_bounds__(256)
void ln_krope(const float* __restrict__ kvf, const float* __restrict__ gamma,
              const float* __restrict__ beta, const float2* __restrict__ tab,
              u16* __restrict__ kvlat, u16* __restrict__ kbuf) {
    int row = blockIdx.x, tid = threadIdx.x;
    const float* x = kvf + (size_t)row * 640;
    float v0 = x[tid], v1 = x[tid + 256];
    float s = v0 + v1, sq = v0 * v0 + v1 * v1;
#pragma unroll
    for (int off = 1; off < 64; off <<= 1) { s += __shfl_xor(s, off); sq += __shfl_xor(sq, off); }
    __shared__ float ssum[4], ssq[4];
    if ((tid & 63) == 0) { ssum[tid >> 6] = s; ssq[tid >> 6] = sq; }
    __syncthreads();
    s = ssum[0] + ssum[1] + ssum[2] + ssum[3];
    sq = ssq[0] + ssq[1] + ssq[2] + ssq[3];
    float mu = s * (1.f / 512.f);
    float var = sq * (1.f / 512.f) - mu * mu;
    float rs = rsqrtf(var + 1e-5f);
    kvlat[(size_t)row * 512 + tid] = f2b((v0 - mu) * rs * gamma[tid] + beta[tid]);
    kvlat[(size_t)row * 512 + tid + 256] = f2b((v1 - mu) * rs * gamma[tid + 256] + beta[tid + 256]);
    if (tid < 32) {
        int t = row & 2047, b = row >> 11;
        float x1 = x[512 + 2 * tid], x2 = x[512 + 2 * tid + 1];
        float2 cs = tab[t * 32 + tid];
        u16 u1 = f2b(x1 * cs.x - x2 * cs.y), u2 = f2b(x1 * cs.y + x2 * cs.x);
        for (int h = 0; h < 16; ++h) {
            size_t base = ((size_t)(b * 16 + h) * 2048 + t) * 192 + 128 + 2 * tid;
            kbuf[base] = u1; kbuf[base + 1] = u2;
        }
    }
}

// ---------------- q RoPE in-place (table) ----------------
__global__ void q_rope(u16* __restrict__ qbuf, const float2* __restrict__ tab) {
    int gid = blockIdx.x * 256 + threadIdx.x;   // 524288 = 32bh * 2048t * 8grp
    int g = gid & 7, t = (gid >> 3) & 2047, bh = gid >> 14;
    size_t base = ((size_t)bh * 2048 + t) * 192 + 128 + g * 8;
    u16x8 v = *(u16x8*)(qbuf + base);
    u16x8 o;
#pragma unroll
    for (int k = 0; k < 4; k++) {
        float2 cs = tab[t * 32 + g * 4 + k];
        float x1 = b2f(v[2 * k]), x2 = b2f(v[2 * k + 1]);
        o[2 * k] = f2b(x1 * cs.x - x2 * cs.y);
        o[2 * k + 1] = f2b(x1 * cs.y + x2 * cs.x);
    }
    *(u16x8*)(qbuf + base) = o;
}

// ---------------- V transpose: vbuf[bh][t][128] -> vtbuf[bh][128][2048] ----------------
__global__ __launch_bounds__(256)
void transpose_v(const u16* __restrict__ vbuf, u16* __restrict__ vtbuf) {
    __shared__ __align__(16) u16 st[64 * 128];
    const int tid = threadIdx.x;
    const int bh = blockIdx.x, t0 = blockIdx.y * 64;
#pragma unroll
    for (int j = 0; j < 4; j++) {
        int c1 = tid + j * 256;
        int t = c1 >> 4, cc = c1 & 15;
        int cs = cc ^ (t & 7) ^ ((t >> 3) & 7);
        bf16x8 v = *(const bf16x8*)(vbuf + ((size_t)bh * 2048 + t0 + t) * 128 + cc * 8);
        *(bf16x8*)&st[t * 128 + cs * 8] = v;
    }
    __syncthreads();
#pragma unroll
    for (int j = 0; j < 4; j++) {
        int c2 = tid + j * 256;
        int d = c2 >> 3, tc8 = (c2 & 7) * 8;
        u16x8 ov;
#pragma unroll
        for (int k2 = 0; k2 < 8; k2++) {
            int t = tc8 + k2;
            int cs = (d >> 3) ^ (t & 7) ^ ((t >> 3) & 7);
            ov[k2] = st[t * 128 + cs * 8 + (d & 7)];
        }
        *(u16x8*)(vtbuf + ((size_t)bh * 128 + d) * 2048 + t0 + tc8) = ov;
    }
}

// ---------------- parallel suffix scan of V -> u term written into attnb ----------------
__global__ void suff1(const u16* __restrict__ vbuf, float* __restrict__ psum) {
    int bh = blockIdx.x, c = blockIdx.y, d = threadIdx.x;   // 128 threads
    float s = 0.f;
    const u16* vp = vbuf + ((size_t)bh * 2048 + c * 128) * 128 + d;
    for (int tt = 0; tt < 128; ++tt) s += b2f(vp[(size_t)tt * 128]);
    psum[((size_t)bh * 16 + c) * 128 + d] = s;
}
__global__ void suff2(const float* __restrict__ psum, float* __restrict__ csuf) {
    int bh = blockIdx.x, d = threadIdx.x;
    float run = 0.f;
    for (int c = 15; c >= 0; --c) {
        csuf[((size_t)bh * 16 + c) * 128 + d] = run;
        run += psum[((size_t)bh * 16 + c) * 128 + d];
    }
}
__global__ void suff3(const u16* __restrict__ vbuf, const float* __restrict__ csuf,
                      u16* __restrict__ attnb) {
    int bh = blockIdx.x, c = blockIdx.y, d = threadIdx.x;
    int b = bh >> 4, h = bh & 15;
    float run = csuf[((size_t)bh * 16 + c) * 128 + d];
    for (int tt = 127; tt >= 0; --tt) {
        int t = c * 128 + tt;
        attnb[((size_t)b * 2048 + t) * 2048 + h * 128 + d] = f2b(run * 0.0625f);
        run += b2f(vbuf[((size_t)bh * 2048 + t) * 128 + d]);
    }
}

// ---------------- Z kernel: Z[b,t,s] = sum_h exp(SCALE * q.k), bf16 ----------------
// double-buffered K+Q staging over h, counted vmcnt, XCD-balanced mapping
__global__ __launch_bounds__(256)
void z_kernel(const u16* __restrict__ qbuf, const u16* __restrict__ kbuf,
              u16* __restrict__ zbuf) {
    __shared__ __align__(16) u16 Qs[2][64 * 192];
    __shared__ __align__(16) u16 Ks[2][64 * 192];
    const int tid = threadIdx.x, lane = tid & 63, wave = tid >> 6;
    int id = blockIdx.x;            // 0..2047
    int xc = id & 7, r = id >> 3;
    int b = xc >> 2, xq = xc & 3;
    int tTile = (r >> 5) * 4 + xq, sTile = r & 31;
    if (sTile > tTile) return;
    const int t0 = tTile * 64, s0 = sTile * 64;
    const int col = lane & 15, koff8 = (lane >> 4) * 8, rowb = (lane >> 4) * 4;

    f32x4 zacc[4];
#pragma unroll
    for (int n = 0; n < 4; n++) zacc[n] = f32x4{0.f, 0.f, 0.f, 0.f};

    auto STAGE = [&](int h, int bi) {
        const size_t hrow = (size_t)(b * 16 + h) * 2048;
#pragma unroll
        for (int j = 0; j < 6; j++) {
            int cidx = (wave * 6 + j) * 64 + lane;
            int rr = cidx / 24, cc = cidx % 24, cs = cc ^ (rr & 7);
            gload_lds16(qbuf + (hrow + t0 + rr) * 192 + cs * 8, &Qs[bi][cidx * 8]);
            gload_lds16(kbuf + (hrow + s0 + rr) * 192 + cs * 8, &Ks[bi][cidx * 8]);
        }
    };
    STAGE(0, 0);
    for (int h = 0; h < 16; ++h) {
        int cur = h & 1;
        if (h + 1 < 16) {
            STAGE(h + 1, cur ^ 1);
            asm volatile("s_waitcnt vmcnt(12)" ::: "memory");
        } else {
            asm volatile("s_waitcnt vmcnt(0)" ::: "memory");
        }
        __builtin_amdgcn_s_barrier();
        __builtin_amdgcn_sched_barrier(0);
        f32x4 e[4];
#pragma unroll
        for (int n = 0; n < 4; n++) e[n] = f32x4{0.f, 0.f, 0.f, 0.f};
        const int qr = wave * 16 + col;
#pragma unroll
        for (int kk = 0; kk < 6; kk++) {
            int ca = kk * 4 + (koff8 >> 3);
            bf16x8 qf = *(const bf16x8*)&Qs[cur][qr * 192 + ((ca ^ (qr & 7)) * 8)];
#pragma unroll
            for (int n = 0; n < 4; n++) {
                int br = n * 16 + col;
                bf16x8 kf = *(const bf16x8*)&Ks[cur][br * 192 + ((ca ^ (br & 7)) * 8)];
                e[n] = __builtin_amdgcn_mfma_f32_16x16x32_bf16(qf, kf, e[n], 0, 0, 0);
            }
        }
#pragma unroll
        for (int n = 0; n < 4; n++)
#pragma unroll
            for (int rr = 0; rr < 4; rr++)
                zacc[n][rr] += __expf(e[n][rr] * SCALE_QK);
        __builtin_amdgcn_s_barrier();
    }
#pragma unroll
    for (int n = 0; n < 4; n++)
#pragma unroll
        for (int rr = 0; rr < 4; rr++) {
            int tg = t0 + wave * 16 + rowb + rr, sg = s0 + n * 16 + col;
            zbuf[((size_t)b * 2048 + tg) * 2048 + sg] = f2b(zacc[n][rr]);
        }
}

// ---------------- PV kernel: attnb += sum_{s<=t} (exp/Z) v ----------------
// paired t-tiles {31-pr, pr}; dbuf K+Vt+Z staging, counted vmcnt; bh grouped per XCD
__global__ __launch_bounds__(256)
void attn_pv(const u16* __restrict__ qbuf, const u16* __restrict__ kbuf,
             const u16* __restrict__ vtbuf, const u16* __restrict__ zbuf,
             u16* __restrict__ attnb) {
    __shared__ __align__(16) u16 Ks[2][64 * 192];   // 48 KB
    __shared__ __align__(16) u16 Vt[2][128 * 64];   // 32 KB
    __shared__ __align__(16) u16 Zs[2][64 * 64];    // 16 KB
    __shared__ __align__(16) u16 Ps[4][16 * 72];    // 9 KB
    const int tid = threadIdx.x, lane = tid & 63, wave = tid >> 6;
    int id = blockIdx.x;          // 0..511
    int xc = id & 7, k = id >> 3;
    int pr = k & 15, bh = xc + ((k >> 4) << 3);
    const int b = bh >> 4, h = bh & 15;
    const int col = lane & 15, koff8 = (lane >> 4) * 8, rowb = (lane >> 4) * 4;
    const size_t kvrow = (size_t)bh * 2048;

    for (int part = 0; part < 2; ++part) {
        const int tTile = (part == 0) ? (31 - pr) : pr;
        const int t0 = tTile * 64, nst = tTile + 1;

        bf16x8 qf[6];
        {
            const u16* qp = qbuf + (kvrow + t0 + wave * 16 + col) * 192 + koff8;
#pragma unroll
            for (int kk = 0; kk < 6; kk++) qf[kk] = *(const bf16x8*)(qp + kk * 32);
        }
        f32x4 o[8];
#pragma unroll
        for (int nt = 0; nt < 8; nt++) o[nt] = f32x4{0.f, 0.f, 0.f, 0.f};

        auto STAGE = [&](int st, int bi) {
            const int s0 = st * 64;
#pragma unroll
            for (int j = 0; j < 6; j++) {
                int cidx = (wave * 6 + j) * 64 + lane;
                int rr = cidx / 24, cc = cidx % 24, cs = cc ^ (rr & 7);
                gload_lds16(kbuf + (kvrow + s0 + rr) * 192 + cs * 8, &Ks[bi][cidx * 8]);
            }
#pragma unroll
            for (int j = 0; j < 4; j++) {
                int cidx = (wave * 4 + j) * 64 + lane;
                int d = cidx >> 3, cc = cidx & 7, cs = cc ^ (d & 7);
                gload_lds16(vtbuf + ((size_t)bh * 128 + d) * 2048 + s0 + cs * 8, &Vt[bi][cidx * 8]);
            }
#pragma unroll
            for (int j = 0; j < 2; j++) {
                int cidx = (wave * 2 + j) * 64 + lane;
                int zr = cidx >> 3, zc = cidx & 7;
                gload_lds16(zbuf + ((size_t)b * 2048 + t0 + zr) * 2048 + s0 + zc * 8, &Zs[bi][cidx * 8]);
            }
        };
        STAGE(0, 0);
        for (int st = 0; st < nst; ++st) {
            int cur = st & 1;
            if (st + 1 < nst) {
                STAGE(st + 1, cur ^ 1);
                asm volatile("s_waitcnt vmcnt(12)" ::: "memory");
            } else {
                asm volatile("s_waitcnt vmcnt(0)" ::: "memory");
            }
            __builtin_amdgcn_s_barrier();
            __builtin_amdgcn_sched_barrier(0);
            const int s0 = st * 64;
            // QK^T
            f32x4 s[4];
#pragma unroll
            for (int n = 0; n < 4; n++) s[n] = f32x4{0.f, 0.f, 0.f, 0.f};
#pragma unroll
            for (int kk = 0; kk < 6; kk++) {
                int ca = kk * 4 + (koff8 >> 3);
#pragma unroll
                for (int n = 0; n < 4; n++) {
                    int br = n * 16 + col;
                    bf16x8 kf = *(const bf16x8*)&Ks[cur][br * 192 + ((ca ^ (br & 7)) * 8)];
                    s[n] = __builtin_amdgcn_mfma_f32_16x16x32_bf16(qf[kk], kf, s[n], 0, 0, 0);
                }
            }
            // w = exp/Z (causal) -> Ps
#pragma unroll
            for (int n = 0; n < 4; n++)
#pragma unroll
                for (int rr = 0; rr < 4; rr++) {
                    int tg = t0 + wave * 16 + rowb + rr, sg = s0 + n * 16 + col;
                    float w = 0.f;
                    if (sg <= tg) {
                        float z = b2f(Zs[cur][(wave * 16 + rowb + rr) * 64 + n * 16 + col]);
                        w = __fdividef(__expf(s[n][rr] * SCALE_QK), z);
                    }
                    Ps[wave][(rowb + rr) * 72 + n * 16 + col] = f2b(w);
                }
            // PV
#pragma unroll
            for (int kk = 0; kk < 2; kk++) {
                bf16x8 pa = *(const bf16x8*)&Ps[wave][col * 72 + kk * 32 + koff8];
                int ca = kk * 4 + (koff8 >> 3);
#pragma unroll
                for (int nt = 0; nt < 8; nt++) {
                    int d = nt * 16 + col;
                    bf16x8 vb = *(const bf16x8*)&Vt[cur][d * 64 + ((ca ^ (d & 7)) * 8)];
                    o[nt] = __builtin_amdgcn_mfma_f32_16x16x32_bf16(pa, vb, o[nt], 0, 0, 0);
                }
            }
            __builtin_amdgcn_s_barrier();
        }
        // epilogue: accumulate into attnb (holds precomputed u term)
#pragma unroll
        for (int nt = 0; nt < 8; nt++)
#pragma unroll
            for (int rr = 0; rr < 4; rr++) {
                int t = t0 + wave * 16 + rowb + rr, d = nt * 16 + col;
                size_t oi = ((size_t)b * 2048 + t) * 2048 + h * 128 + d;
                attnb[oi] = f2b(o[nt][rr] + b2f(attnb[oi]));
            }
    }
}

// ---------------- launch ----------------
extern "C" void kernel_launch(void* const* d_in, const int* in_sizes, int n_in,
                              void* d_out, int out_size, void* d_ws, size_t ws_size,
                              hipStream_t stream) {
    (void)in_sizes; (void)n_in; (void)out_size;
    const float* hidden = (const float*)d_in[0];
    const float* freqs  = (const float*)d_in[1];
    const float* Wq     = (const float*)d_in[3];
    const float* Wkva   = (const float*)d_in[4];
    const float* gamma  = (const float*)d_in[5];
    const float* beta   = (const float*)d_in[6];
    const float* Wkvb   = (const float*)d_in[7];
    const float* Wout   = (const float*)d_in[8];
    float* outp = (float*)d_out;

    char* ws = (char*)d_ws;
    size_t off = 0;
    auto alloc = [&](size_t bytes) -> void* {
        void* p = ws + off; off += (bytes + 255) & ~(size_t)255; return p;
    };
    u16*   hid_b = (u16*)alloc((size_t)MROWS * HID * 2);
    u16*   WqT   = (u16*)alloc((size_t)3072 * 2048 * 2);
    u16*   WkvaT = (u16*)alloc((size_t)640 * 2048 * 2);
    u16*   WkvbT = (u16*)alloc((size_t)4096 * 512 * 2);
    u16*   WoutT = (u16*)alloc((size_t)2048 * 2048 * 2);
    u16*   qbuf  = (u16*)alloc((size_t)BATCH * NHEAD * TSEQ * QK * 2);
    float* kvf   = (float*)alloc((size_t)MROWS * 640 * 4);
    u16*   kvlat = (u16*)alloc((size_t)MROWS * 512 * 2);
    u16*   kbuf  = (u16*)alloc((size_t)BATCH * NHEAD * TSEQ * QK * 2);
    u16*   vbuf  = (u16*)alloc((size_t)BATCH * NHEAD * TSEQ * VD * 2);
    u16*   attnb = (u16*)alloc((size_t)MROWS * 2048 * 2);
    float2* ropetab = (float2*)alloc((size_t)2048 * 32 * 8);
    float* psum  = (float*)alloc((size_t)32 * 16 * 128 * 4);
    float* csuf  = (float*)alloc((size_t)32 * 16 * 128 * 4);
    if (off > ws_size) return;
    // overlays (dead regions by the time they're written):
    u16* zbuf  = WqT;     // 16.78 MB over WqT+WkvaT+WkvbT, free after gemm<0>/<2>
    u16* vtbuf = hid_b;   // 16.78 MB, free after gemm<0>

    cvt_bf16x8<<<4096, 256, 0, stream>>>(hidden, hid_b, MROWS * HID / 8);
    rope_tab_k<<<256, 256, 0, stream>>>(freqs, ropetab);
    dim3 tb(32, 8);
    transpose_cvt<<<dim3(96, 64), tb, 0, stream>>>(Wq, WqT, 2048, 3072, 3072);
    transpose_cvt<<<dim3(20, 64), tb, 0, stream>>>(Wkva, WkvaT, 2048, 576, 640);
    transpose_cvt<<<dim3(128, 16), tb, 0, stream>>>(Wkvb, WkvbT, 512, 4096, 4096);
    transpose_cvt<<<dim3(64, 64), tb, 0, stream>>>(Wout, WoutT, 2048, 2048, 2048);

    gemm_bt<1><<<dim3(32, 5), 256, 0, stream>>>(hid_b, WkvaT, 2048, kvf, nullptr);
    ln_krope<<<MROWS, 256, 0, stream>>>(kvf, gamma, beta, ropetab, kvlat, kbuf);
    gemm_bt<2><<<dim3(32, 32), 256, 0, stream>>>(kvlat, WkvbT, 512, kbuf, vbuf);
    gemm_bt<0><<<dim3(32, 24), 256, 0, stream>>>(hid_b, WqT, 2048, qbuf, nullptr);
    q_rope<<<2048, 256, 0, stream>>>(qbuf, ropetab);

    transpose_v<<<dim3(32, 32), 256, 0, stream>>>(vbuf, vtbuf);
    suff1<<<dim3(32, 16), 128, 0, stream>>>(vbuf, psum);
    suff2<<<32, 128, 0, stream>>>(psum, csuf);
    suff3<<<dim3(32, 16), 128, 0, stream>>>(vbuf, csuf, attnb);

    z_kernel<<<2048, 256, 0, stream>>>(qbuf, kbuf, zbuf);
    attn_pv<<<512, 256, 0, stream>>>(qbuf, kbuf, vtbuf, zbuf, attnb);

    gemm_bt<3><<<dim3(32, 16), 256, 0, stream>>>(attnb, WoutT, 2048, outp, nullptr);
}

// Round 4
// 439.283 us; speedup vs baseline: 1.9400x; 1.2803x over previous
//
#include <hip/hip_runtime.h>

typedef unsigned short u16;
typedef short bf16x8 __attribute__((ext_vector_type(8)));
typedef float f32x4 __attribute__((ext_vector_type(4)));
typedef unsigned short u16x8 __attribute__((ext_vector_type(8)));

#define GLOBAL_AS __attribute__((address_space(1)))
#define LDS_AS __attribute__((address_space(3)))
#define DEVINL __device__ __forceinline__

#define BATCH 2
#define TSEQ 2048
#define NHEAD 16
#define QK 192
#define VD 128
#define HID 2048
#define MROWS 4096
#define SCALE_QK 0.07216878364870323f   // 192^-0.5

DEVINL float b2f(u16 u) { union { unsigned i; float f; } x; x.i = ((unsigned)u) << 16; return x.f; }
DEVINL u16 f2b(float f) {
    union { float f; unsigned u; } x; x.f = f;
    unsigned r = x.u + 0x7fffu + ((x.u >> 16) & 1u);
    return (u16)(r >> 16);
}
DEVINL void gload_lds16(const u16* g, u16* l) {
    __builtin_amdgcn_global_load_lds((const GLOBAL_AS unsigned*)g, (LDS_AS unsigned*)l, 16, 0, 0);
}

// ---------------- conversion kernels ----------------

__global__ void cvt_bf16x8(const float* __restrict__ in, u16* __restrict__ out, int n8) {
    int i = blockIdx.x * 256 + threadIdx.x;
    if (i < n8) {
        const float4* p = (const float4*)(in + (size_t)i * 8);
        float4 x = p[0], y = p[1];
        u16x8 o;
        o[0] = f2b(x.x); o[1] = f2b(x.y); o[2] = f2b(x.z); o[3] = f2b(x.w);
        o[4] = f2b(y.x); o[5] = f2b(y.y); o[6] = f2b(y.z); o[7] = f2b(y.w);
        *(u16x8*)(out + (size_t)i * 8) = o;
    }
}

__global__ void rope_tab_k(const float* __restrict__ freqs, float2* __restrict__ tab) {
    int i = blockIdx.x * 256 + threadIdx.x;   // 65536 = 2048*32
    float f = freqs[i], s, c;
    sincosf(f, &s, &c);
    tab[i] = make_float2(c, s);
}

// in: f32 [R][C] row-major -> out: bf16 [Cpad][R], zeros for c >= C
__global__ void transpose_cvt(const float* __restrict__ in, u16* __restrict__ out,
                              int R, int C, int Cpad) {
    __shared__ float tile[32][33];
    int c0 = blockIdx.x * 32, r0 = blockIdx.y * 32;
    int tx = threadIdx.x, ty = threadIdx.y;   // 32 x 8
#pragma unroll
    for (int j = 0; j < 4; j++) {
        int r = r0 + ty + j * 8, c = c0 + tx;
        tile[ty + j * 8][tx] = (c < C) ? in[(size_t)r * C + c] : 0.f;
    }
    __syncthreads();
#pragma unroll
    for (int j = 0; j < 4; j++) {
        int oc = c0 + ty + j * 8;
        int orr = r0 + tx;
        if (oc < Cpad) out[(size_t)oc * R + orr] = f2b(tile[tx][ty + j * 8]);
    }
}

// ---------------- GEMM: C = A[M][K] * BT[N][K]^T ----------------
template<int MODE>
__global__ __launch_bounds__(256)
void gemm_bt(const u16* __restrict__ A, const u16* __restrict__ BT, int Kdim,
             void* __restrict__ out0, void* __restrict__ out1) {
    __shared__ __align__(16) u16 As[128 * 32];
    __shared__ __align__(16) u16 Bs[128 * 32];
    const int tid = threadIdx.x, lane = tid & 63, wave = tid >> 6;
    const int m0 = blockIdx.x * 128, n0 = blockIdx.y * 128;
    const int wr = wave >> 1, wc = wave & 1;

    f32x4 acc[4][4];
#pragma unroll
    for (int i = 0; i < 4; i++)
#pragma unroll
        for (int j = 0; j < 4; j++) acc[i][j] = f32x4{0.f, 0.f, 0.f, 0.f};

    const int e0 = (wave * 2 + 0) * 512 + lane * 8;
    const int e1 = (wave * 2 + 1) * 512 + lane * 8;
    const u16* gA0 = A + (size_t)(m0 + (e0 >> 5)) * Kdim + (e0 & 31);
    const u16* gA1 = A + (size_t)(m0 + (e1 >> 5)) * Kdim + (e1 & 31);
    const u16* gB0 = BT + (size_t)(n0 + (e0 >> 5)) * Kdim + (e0 & 31);
    const u16* gB1 = BT + (size_t)(n0 + (e1 >> 5)) * Kdim + (e1 & 31);
    u16* lA0 = &As[(wave * 2 + 0) * 512];
    u16* lA1 = &As[(wave * 2 + 1) * 512];
    u16* lB0 = &Bs[(wave * 2 + 0) * 512];
    u16* lB1 = &Bs[(wave * 2 + 1) * 512];

    const int arow = lane & 15, koff = (lane >> 4) * 8;

    for (int k0 = 0; k0 < Kdim; k0 += 32) {
        gload_lds16(gA0, lA0); gload_lds16(gA1, lA1);
        gload_lds16(gB0, lB0); gload_lds16(gB1, lB1);
        gA0 += 32; gA1 += 32; gB0 += 32; gB1 += 32;
        asm volatile("s_waitcnt vmcnt(0)" ::: "memory");
        __syncthreads();
        bf16x8 af[4], bfr[4];
#pragma unroll
        for (int i = 0; i < 4; i++)
            af[i] = *(const bf16x8*)&As[(wr * 64 + i * 16 + arow) * 32 + koff];
#pragma unroll
        for (int j = 0; j < 4; j++)
            bfr[j] = *(const bf16x8*)&Bs[(wc * 64 + j * 16 + arow) * 32 + koff];
#pragma unroll
        for (int i = 0; i < 4; i++)
#pragma unroll
            for (int j = 0; j < 4; j++)
                acc[i][j] = __builtin_amdgcn_mfma_f32_16x16x32_bf16(af[i], bfr[j], acc[i][j], 0, 0, 0);
        __syncthreads();
    }

#pragma unroll
    for (int i = 0; i < 4; i++)
#pragma unroll
        for (int j = 0; j < 4; j++)
#pragma unroll
            for (int r = 0; r < 4; r++) {
                int row = m0 + wr * 64 + i * 16 + (lane >> 4) * 4 + r;
                int col = n0 + wc * 64 + j * 16 + (lane & 15);
                float v = acc[i][j][r];
                if constexpr (MODE == 0) {
                    int h = col / 192, d = col % 192;
                    int b = row >> 11, t = row & 2047;
                    ((u16*)out0)[((size_t)(b * 16 + h) * 2048 + t) * 192 + d] = f2b(v);
                } else if constexpr (MODE == 1) {
                    ((float*)out0)[(size_t)row * 640 + col] = v;
                } else if constexpr (MODE == 2) {
                    int h = col >> 8, d = col & 255;
                    int b = row >> 11, t = row & 2047;
                    size_t base = (size_t)(b * 16 + h) * 2048 + t;
                    if (d < 128) ((u16*)out0)[base * 192 + d] = f2b(v);
                    else         ((u16*)out1)[base * 128 + (d - 128)] = f2b(v);
                } else {
                    ((float*)out0)[(size_t)row * 2048 + col] = v;
                }
            }
}

// ---------------- LayerNorm(512) + k_rope broadcast ----------------
__global__ __launch_bounds__(256)
void ln_krope(const float* __restrict__ kvf, const float* __restrict__ gamma,
              const float* __restrict__ beta, const float2* __restrict__ tab,
              u16* __restrict__ kvlat, u16* __restrict__ kbuf) {
    int row = blockIdx.x, tid = threadIdx.x;
    const float* x = kvf + (size_t)row * 640;
    float v0 = x[tid], v1 = x[tid + 256];
    float s = v0 + v1, sq = v0 * v0 + v1 * v1;
#pragma unroll
    for (int off = 1; off < 64; off <<= 1) { s += __shfl_xor(s, off); sq += __shfl_xor(sq, off); }
    __shared__ float ssum[4], ssq[4];
    if ((tid & 63) == 0) { ssum[tid >> 6] = s; ssq[tid >> 6] = sq; }
    __syncthreads();
    s = ssum[0] + ssum[1] + ssum[2] + ssum[3];
    sq = ssq[0] + ssq[1] + ssq[2] + ssq[3];
    float mu = s * (1.f / 512.f);
    float var = sq * (1.f / 512.f) - mu * mu;
    float rs = rsqrtf(var + 1e-5f);
    kvlat[(size_t)row * 512 + tid] = f2b((v0 - mu) * rs * gamma[tid] + beta[tid]);
    kvlat[(size_t)row * 512 + tid + 256] = f2b((v1 - mu) * rs * gamma[tid + 256] + beta[tid + 256]);
    if (tid < 32) {
        int t = row & 2047, b = row >> 11;
        float x1 = x[512 + 2 * tid], x2 = x[512 + 2 * tid + 1];
        float2 cs = tab[t * 32 + tid];
        u16 u1 = f2b(x1 * cs.x - x2 * cs.y), u2 = f2b(x1 * cs.y + x2 * cs.x);
        for (int h = 0; h < 16; ++h) {
            size_t base = ((size_t)(b * 16 + h) * 2048 + t) * 192 + 128 + 2 * tid;
            kbuf[base] = u1; kbuf[base + 1] = u2;
        }
    }
}

// ---------------- q RoPE in-place (table) ----------------
__global__ void q_rope(u16* __restrict__ qbuf, const float2* __restrict__ tab) {
    int gid = blockIdx.x * 256 + threadIdx.x;   // 524288 = 32bh * 2048t * 8grp
    int g = gid & 7, t = (gid >> 3) & 2047, bh = gid >> 14;
    size_t base = ((size_t)bh * 2048 + t) * 192 + 128 + g * 8;
    u16x8 v = *(u16x8*)(qbuf + base);
    u16x8 o;
#pragma unroll
    for (int k = 0; k < 4; k++) {
        float2 cs = tab[t * 32 + g * 4 + k];
        float x1 = b2f(v[2 * k]), x2 = b2f(v[2 * k + 1]);
        o[2 * k] = f2b(x1 * cs.x - x2 * cs.y);
        o[2 * k + 1] = f2b(x1 * cs.y + x2 * cs.x);
    }
    *(u16x8*)(qbuf + base) = o;
}

// ---------------- V transpose: vbuf[bh][t][128] -> vtbuf[bh][128][2048] ----------------
__global__ __launch_bounds__(256)
void transpose_v(const u16* __restrict__ vbuf, u16* __restrict__ vtbuf) {
    __shared__ __align__(16) u16 st[64 * 128];
    const int tid = threadIdx.x;
    const int bh = blockIdx.x, t0 = blockIdx.y * 64;
#pragma unroll
    for (int j = 0; j < 4; j++) {
        int c1 = tid + j * 256;
        int t = c1 >> 4, cc = c1 & 15;
        int cs = cc ^ (t & 7) ^ ((t >> 3) & 7);
        bf16x8 v = *(const bf16x8*)(vbuf + ((size_t)bh * 2048 + t0 + t) * 128 + cc * 8);
        *(bf16x8*)&st[t * 128 + cs * 8] = v;
    }
    __syncthreads();
#pragma unroll
    for (int j = 0; j < 4; j++) {
        int c2 = tid + j * 256;
        int d = c2 >> 3, tc8 = (c2 & 7) * 8;
        u16x8 ov;
#pragma unroll
        for (int k2 = 0; k2 < 8; k2++) {
            int t = tc8 + k2;
            int cs = (d >> 3) ^ (t & 7) ^ ((t >> 3) & 7);
            ov[k2] = st[t * 128 + cs * 8 + (d & 7)];
        }
        *(u16x8*)(vtbuf + ((size_t)bh * 128 + d) * 2048 + t0 + tc8) = ov;
    }
}

// ---------------- parallel suffix scan of V -> u term written into attnb ----------------
__global__ void suff1(const u16* __restrict__ vbuf, float* __restrict__ psum) {
    int bh = blockIdx.x, c = blockIdx.y, d = threadIdx.x;   // 128 threads
    float s = 0.f;
    const u16* vp = vbuf + ((size_t)bh * 2048 + c * 128) * 128 + d;
    for (int tt = 0; tt < 128; ++tt) s += b2f(vp[(size_t)tt * 128]);
    psum[((size_t)bh * 16 + c) * 128 + d] = s;
}
__global__ void suff2(const float* __restrict__ psum, float* __restrict__ csuf) {
    int bh = blockIdx.x, d = threadIdx.x;
    float run = 0.f;
    for (int c = 15; c >= 0; --c) {
        csuf[((size_t)bh * 16 + c) * 128 + d] = run;
        run += psum[((size_t)bh * 16 + c) * 128 + d];
    }
}
__global__ void suff3(const u16* __restrict__ vbuf, const float* __restrict__ csuf,
                      u16* __restrict__ attnb) {
    int bh = blockIdx.x, c = blockIdx.y, d = threadIdx.x;
    int b = bh >> 4, h = bh & 15;
    float run = csuf[((size_t)bh * 16 + c) * 128 + d];
    for (int tt = 127; tt >= 0; --tt) {
        int t = c * 128 + tt;
        attnb[((size_t)b * 2048 + t) * 2048 + h * 128 + d] = f2b(run * 0.0625f);
        run += b2f(vbuf[((size_t)bh * 2048 + t) * 128 + d]);
    }
}

// ---------------- Z kernel: zbuf[b,t,s] = 1 / sum_h exp(SCALE*q.k), bf16 ----------------
// Q in registers (2-bank prefetch), K dbuf LDS (48KB -> 3 blocks/CU), compact tri grid
__global__ __launch_bounds__(256, 3)
void z_kernel(const u16* __restrict__ qbuf, const u16* __restrict__ kbuf,
              u16* __restrict__ zbuf) {
    __shared__ __align__(16) u16 Ks[2][64 * 192];
    const int tid = threadIdx.x, lane = tid & 63, wave = tid >> 6;
    int id = blockIdx.x;            // 0..1055
    int b = id & 1, p = id >> 1;    // p in [0,528)
    int tT = (int)((sqrtf(8.f * (float)p + 1.f) - 1.f) * 0.5f);
    while ((tT + 1) * (tT + 2) / 2 <= p) ++tT;
    while (tT * (tT + 1) / 2 > p) --tT;
    int sT = p - tT * (tT + 1) / 2;
    const int t0 = tT * 64, s0 = sT * 64;
    const int col = lane & 15, koff8 = (lane >> 4) * 8, rowb = (lane >> 4) * 4;
    const int qrow = t0 + wave * 16 + col;

    f32x4 zacc[4];
#pragma unroll
    for (int n = 0; n < 4; n++) zacc[n] = f32x4{0.f, 0.f, 0.f, 0.f};

    auto QLOAD = [&](int h, bf16x8 (&q)[6]) {
        const u16* qp = qbuf + ((size_t)(b * 16 + h) * 2048 + qrow) * 192 + koff8;
#pragma unroll
        for (int kk = 0; kk < 6; kk++) q[kk] = *(const bf16x8*)(qp + kk * 32);
    };
    auto KSTAGE = [&](int h, int bi) {
        const size_t hrow = (size_t)(b * 16 + h) * 2048;
#pragma unroll
        for (int j = 0; j < 6; j++) {
            int cidx = (wave * 6 + j) * 64 + lane;
            int rr2 = cidx / 24, cc = cidx % 24, cs = cc ^ (rr2 & 7);
            gload_lds16(kbuf + (hrow + s0 + rr2) * 192 + cs * 8, &Ks[bi][cidx * 8]);
        }
    };
    auto COMPUTE = [&](const bf16x8 (&q)[6], const u16* K) {
        f32x4 e[4];
#pragma unroll
        for (int n = 0; n < 4; n++) e[n] = f32x4{0.f, 0.f, 0.f, 0.f};
#pragma unroll
        for (int kk = 0; kk < 6; kk++) {
            int ca = kk * 4 + (lane >> 4);
#pragma unroll
            for (int n = 0; n < 4; n++) {
                int br = n * 16 + col;
                bf16x8 kf = *(const bf16x8*)&K[br * 192 + ((ca ^ (br & 7)) * 8)];
                e[n] = __builtin_amdgcn_mfma_f32_16x16x32_bf16(q[kk], kf, e[n], 0, 0, 0);
            }
        }
#pragma unroll
        for (int n = 0; n < 4; n++)
#pragma unroll
            for (int r = 0; r < 4; r++)
                zacc[n][r] += __expf(e[n][r] * SCALE_QK);
    };

    bf16x8 qA[6], qB[6];
    QLOAD(0, qA);
    KSTAGE(0, 0);
    for (int hh = 0; hh < 8; ++hh) {
        int h0 = hh * 2;
        QLOAD(h0 + 1, qB);
        KSTAGE(h0 + 1, 1);
        asm volatile("s_waitcnt vmcnt(12)" ::: "memory");
        __builtin_amdgcn_s_barrier();
        __builtin_amdgcn_sched_barrier(0);
        COMPUTE(qA, &Ks[0][0]);
        __builtin_amdgcn_s_barrier();
        if (hh < 7) {
            QLOAD(h0 + 2, qA);
            KSTAGE(h0 + 2, 0);
            asm volatile("s_waitcnt vmcnt(12)" ::: "memory");
        } else {
            asm volatile("s_waitcnt vmcnt(0)" ::: "memory");
        }
        __builtin_amdgcn_s_barrier();
        __builtin_amdgcn_sched_barrier(0);
        COMPUTE(qB, &Ks[1][0]);
        __builtin_amdgcn_s_barrier();
    }
#pragma unroll
    for (int n = 0; n < 4; n++)
#pragma unroll
        for (int r = 0; r < 4; r++) {
            int tg = t0 + wave * 16 + rowb + r, sg = s0 + n * 16 + col;
            zbuf[((size_t)b * 2048 + tg) * 2048 + sg] = f2b(__fdividef(1.f, zacc[n][r]));
        }
}

// ---------------- PV kernel: attnb += sum_{s<=t} exp(x)*rz * v ----------------
// 8 waves, t-tile 128, pairs {T,15-T} (34 s-iters/block), K/V/Z dbuf, vmcnt(7)
__global__ __launch_bounds__(512, 2)
void attn_pv(const u16* __restrict__ qbuf, const u16* __restrict__ kbuf,
             const u16* __restrict__ vtbuf, const u16* __restrict__ zbuf,
             u16* __restrict__ attnb) {
    __shared__ __align__(16) u16 Ks[2][64 * 192];    // 48 KB
    __shared__ __align__(16) u16 Vt[2][128 * 64];    // 32 KB
    __shared__ __align__(16) u16 Zs[2][128 * 64];    // 32 KB
    __shared__ __align__(16) u16 Ps[8][16 * 72];     // 18 KB
    const int tid = threadIdx.x, lane = tid & 63, wave = tid >> 6;
    int id = blockIdx.x;             // 0..255
    int xcd = id & 7, j2 = id >> 3;
    int pr = j2 & 7, g = j2 >> 3;
    int bh = xcd * 4 + g;
    const int b = bh >> 4, h = bh & 15;
    const int col = lane & 15, koff8 = (lane >> 4) * 8, rowb = (lane >> 4) * 4;
    const size_t kvrow = (size_t)bh * 2048;

    for (int part = 0; part < 2; ++part) {
        const int T = part ? (15 - pr) : pr;
        const int t0 = T * 128, nst = 2 * T + 2;

        bf16x8 qf[6];
        {
            const u16* qp = qbuf + (kvrow + t0 + wave * 16 + col) * 192 + koff8;
#pragma unroll
            for (int kk = 0; kk < 6; kk++) qf[kk] = *(const bf16x8*)(qp + kk * 32);
        }
        f32x4 o[8];
#pragma unroll
        for (int nt = 0; nt < 8; nt++) o[nt] = f32x4{0.f, 0.f, 0.f, 0.f};

        auto STAGE = [&](int st, int bi) {
            const int s0 = st * 64;
#pragma unroll
            for (int j = 0; j < 3; j++) {
                int cidx = (wave * 3 + j) * 64 + lane;
                int rr2 = cidx / 24, cc = cidx % 24, cs = cc ^ (rr2 & 7);
                gload_lds16(kbuf + (kvrow + s0 + rr2) * 192 + cs * 8, &Ks[bi][cidx * 8]);
            }
#pragma unroll
            for (int j = 0; j < 2; j++) {
                int cidx = (wave * 2 + j) * 64 + lane;
                int d = cidx >> 3, cc = cidx & 7, cs = cc ^ (d & 7);
                gload_lds16(vtbuf + ((size_t)bh * 128 + d) * 2048 + s0 + cs * 8, &Vt[bi][cidx * 8]);
            }
#pragma unroll
            for (int j = 0; j < 2; j++) {
                int cidx = (wave * 2 + j) * 64 + lane;
                int zr = cidx >> 3, zc = cidx & 7, zcs = zc ^ (zr & 7);
                gload_lds16(zbuf + ((size_t)b * 2048 + t0 + zr) * 2048 + s0 + zcs * 8, &Zs[bi][cidx * 8]);
            }
        };
        STAGE(0, 0);
        for (int st = 0; st < nst; ++st) {
            int cur = st & 1;
            if (st + 1 < nst) {
                STAGE(st + 1, cur ^ 1);
                asm volatile("s_waitcnt vmcnt(7)" ::: "memory");
            } else {
                asm volatile("s_waitcnt vmcnt(0)" ::: "memory");
            }
            __builtin_amdgcn_s_barrier();
            __builtin_amdgcn_sched_barrier(0);
            const int s0 = st * 64;
            // QK^T
            f32x4 sc[4];
#pragma unroll
            for (int n = 0; n < 4; n++) sc[n] = f32x4{0.f, 0.f, 0.f, 0.f};
#pragma unroll
            for (int kk = 0; kk < 6; kk++) {
                int ca = kk * 4 + (lane >> 4);
#pragma unroll
                for (int n = 0; n < 4; n++) {
                    int br = n * 16 + col;
                    bf16x8 kf = *(const bf16x8*)&Ks[cur][br * 192 + ((ca ^ (br & 7)) * 8)];
                    sc[n] = __builtin_amdgcn_mfma_f32_16x16x32_bf16(qf[kk], kf, sc[n], 0, 0, 0);
                }
            }
            // w = exp(x) * rz (causal) -> Ps
#pragma unroll
            for (int n = 0; n < 4; n++)
#pragma unroll
                for (int rr = 0; rr < 4; rr++) {
                    int tr = wave * 16 + rowb + rr;
                    int tg = t0 + tr, sg = s0 + n * 16 + col;
                    float w = 0.f;
                    if (sg <= tg) {
                        int sl = n * 16 + col;
                        float rz = b2f(Zs[cur][tr * 64 + (((sl >> 3) ^ (tr & 7)) << 3) + (sl & 7)]);
                        w = __expf(sc[n][rr] * SCALE_QK) * rz;
                    }
                    Ps[wave][(rowb + rr) * 72 + n * 16 + col] = f2b(w);
                }
            // PV
#pragma unroll
            for (int kk = 0; kk < 2; kk++) {
                bf16x8 pa = *(const bf16x8*)&Ps[wave][col * 72 + kk * 32 + koff8];
                int ca = kk * 4 + (lane >> 4);
#pragma unroll
                for (int nt = 0; nt < 8; nt++) {
                    int d = nt * 16 + col;
                    bf16x8 vb = *(const bf16x8*)&Vt[cur][d * 64 + ((ca ^ (d & 7)) * 8)];
                    o[nt] = __builtin_amdgcn_mfma_f32_16x16x32_bf16(pa, vb, o[nt], 0, 0, 0);
                }
            }
            __builtin_amdgcn_s_barrier();
        }
        // epilogue: accumulate into attnb (holds precomputed u term)
#pragma unroll
        for (int nt = 0; nt < 8; nt++)
#pragma unroll
            for (int rr = 0; rr < 4; rr++) {
                int t = t0 + wave * 16 + rowb + rr, d = nt * 16 + col;
                size_t oi = ((size_t)b * 2048 + t) * 2048 + h * 128 + d;
                attnb[oi] = f2b(o[nt][rr] + b2f(attnb[oi]));
            }
    }
}

// ---------------- launch ----------------
extern "C" void kernel_launch(void* const* d_in, const int* in_sizes, int n_in,
                              void* d_out, int out_size, void* d_ws, size_t ws_size,
                              hipStream_t stream) {
    (void)in_sizes; (void)n_in; (void)out_size;
    const float* hidden = (const float*)d_in[0];
    const float* freqs  = (const float*)d_in[1];
    const float* Wq     = (const float*)d_in[3];
    const float* Wkva   = (const float*)d_in[4];
    const float* gamma  = (const float*)d_in[5];
    const float* beta   = (const float*)d_in[6];
    const float* Wkvb   = (const float*)d_in[7];
    const float* Wout   = (const float*)d_in[8];
    float* outp = (float*)d_out;

    char* ws = (char*)d_ws;
    size_t off = 0;
    auto alloc = [&](size_t bytes) -> void* {
        void* p = ws + off; off += (bytes + 255) & ~(size_t)255; return p;
    };
    u16*   hid_b = (u16*)alloc((size_t)MROWS * HID * 2);
    u16*   WqT   = (u16*)alloc((size_t)3072 * 2048 * 2);
    u16*   WkvaT = (u16*)alloc((size_t)640 * 2048 * 2);
    u16*   WkvbT = (u16*)alloc((size_t)4096 * 512 * 2);
    u16*   WoutT = (u16*)alloc((size_t)2048 * 2048 * 2);
    u16*   qbuf  = (u16*)alloc((size_t)BATCH * NHEAD * TSEQ * QK * 2);
    float* kvf   = (float*)alloc((size_t)MROWS * 640 * 4);
    u16*   kvlat = (u16*)alloc((size_t)MROWS * 512 * 2);
    u16*   kbuf  = (u16*)alloc((size_t)BATCH * NHEAD * TSEQ * QK * 2);
    u16*   vbuf  = (u16*)alloc((size_t)BATCH * NHEAD * TSEQ * VD * 2);
    u16*   attnb = (u16*)alloc((size_t)MROWS * 2048 * 2);
    float2* ropetab = (float2*)alloc((size_t)2048 * 32 * 8);
    float* psum  = (float*)alloc((size_t)32 * 16 * 128 * 4);
    float* csuf  = (float*)alloc((size_t)32 * 16 * 128 * 4);
    if (off > ws_size) return;
    // overlays (dead regions by the time they're written):
    u16* zbuf  = WqT;     // 16.78 MB over WqT+WkvaT+WkvbT, free after gemm<0>/<2>
    u16* vtbuf = hid_b;   // 16.78 MB, free after gemm<0>

    cvt_bf16x8<<<4096, 256, 0, stream>>>(hidden, hid_b, MROWS * HID / 8);
    rope_tab_k<<<256, 256, 0, stream>>>(freqs, ropetab);
    dim3 tb(32, 8);
    transpose_cvt<<<dim3(96, 64), tb, 0, stream>>>(Wq, WqT, 2048, 3072, 3072);
    transpose_cvt<<<dim3(20, 64), tb, 0, stream>>>(Wkva, WkvaT, 2048, 576, 640);
    transpose_cvt<<<dim3(128, 16), tb, 0, stream>>>(Wkvb, WkvbT, 512, 4096, 4096);
    transpose_cvt<<<dim3(64, 64), tb, 0, stream>>>(Wout, WoutT, 2048, 2048, 2048);

    gemm_bt<1><<<dim3(32, 5), 256, 0, stream>>>(hid_b, WkvaT, 2048, kvf, nullptr);
    ln_krope<<<MROWS, 256, 0, stream>>>(kvf, gamma, beta, ropetab, kvlat, kbuf);
    gemm_bt<2><<<dim3(32, 32), 256, 0, stream>>>(kvlat, WkvbT, 512, kbuf, vbuf);
    gemm_bt<0><<<dim3(32, 24), 256, 0, stream>>>(hid_b, WqT, 2048, qbuf, nullptr);
    q_rope<<<2048, 256, 0, stream>>>(qbuf, ropetab);

    transpose_v<<<dim3(32, 32), 256, 0, stream>>>(vbuf, vtbuf);
    suff1<<<dim3(32, 16), 128, 0, stream>>>(vbuf, psum);
    suff2<<<32, 128, 0, stream>>>(psum, csuf);
    suff3<<<dim3(32, 16), 128, 0, stream>>>(vbuf, csuf, attnb);

    z_kernel<<<1056, 256, 0, stream>>>(qbuf, kbuf, zbuf);
    attn_pv<<<256, 512, 0, stream>>>(qbuf, kbuf, vtbuf, zbuf, attnb);

    gemm_bt<3><<<dim3(32, 16), 256, 0, stream>>>(attnb, WoutT, 2048, outp, nullptr);
}